// Round 1
// baseline (125.853 us; speedup 1.0000x reference)
//
#include <hip/hip_runtime.h>

namespace {

constexpr int Tt = 32;    // frames (t)
constexpr int Ss = 784;   // h*w = 28*28

// ---------------------------------------------------------------------------
// Kernel 1: per-(b,c) partial Gram.
//   part[blk][q*32+k] = sum_s x[blk][q][s] * x[blk][k][s],  blk = b*64+c
// 1024 blocks x 256 threads. LDS tile [32][128] fp32 stored as float4 with an
// XOR swizzle (col4 ^ ((row>>2)&7)) so q-strided b128 reads are conflict-free.
// Double-buffered (reg-staged prefetch, one barrier per chunk).
// ---------------------------------------------------------------------------
__global__ __launch_bounds__(256) void gram_partial(const float* __restrict__ x,
                                                    float* __restrict__ part) {
  const int blk = blockIdx.x;                       // b*64 + c
  const float* __restrict__ xb = x + (size_t)blk * (Tt * Ss);
  const int tid  = threadIdx.x;
  const int w    = tid >> 6;      // wave 0..3
  const int lane = tid & 63;
  const int ty   = lane >> 3;     // q-group 0..7
  const int tx   = lane & 7;      // k-group 0..7
  const int r0   = tid >> 5;      // staging row base 0..7
  const int col4 = tid & 31;      // staging float4 column 0..31

  __shared__ float4 tile[2][32][32];   // 2 x 16 KB
  __shared__ float  mtmp[4][1024];     // 16 KB wave-reduction buffer

  float acc[4][4];
#pragma unroll
  for (int i = 0; i < 4; ++i)
#pragma unroll
    for (int j = 0; j < 4; ++j) acc[i][j] = 0.f;

  // prologue: stage chunk 0 (s = 0..127)
#pragma unroll
  for (int l = 0; l < 4; ++l) {
    const int row = r0 + 8 * l;
    const float4 v = *reinterpret_cast<const float4*>(xb + row * Ss + 4 * col4);
    tile[0][row][col4 ^ ((row >> 2) & 7)] = v;
  }
  __syncthreads();

  for (int ch = 0; ch < 7; ++ch) {    // 784 = 6*128 + 16
    const int buf = ch & 1;

    // prefetch next chunk into registers (latency hides under compute)
    float4 nxt[4];
    const int s0n = (ch + 1) * 128;
    const bool pf = (ch < 6) && (s0n + 4 * col4 < Ss);
    if (pf) {
#pragma unroll
      for (int l = 0; l < 4; ++l) {
        const int row = r0 + 8 * l;
        nxt[l] = *reinterpret_cast<const float4*>(xb + row * Ss + s0n + 4 * col4);
      }
    }

    int s4max = (Ss - ch * 128) >> 2;   // 32 for full chunks, 4 for the tail
    if (s4max > 32) s4max = 32;
#pragma unroll
    for (int sc = 0; sc < 8; ++sc) {
      const int s4 = w * 8 + sc;        // this wave's float4-column in chunk
      if (s4 < s4max) {
        float4 a4[4], b4[4];
#pragma unroll
        for (int i = 0; i < 4; ++i) a4[i] = tile[buf][4 * ty + i][s4 ^ ty];
#pragma unroll
        for (int j = 0; j < 4; ++j) b4[j] = tile[buf][4 * tx + j][s4 ^ tx];
#pragma unroll
        for (int i = 0; i < 4; ++i)
#pragma unroll
          for (int j = 0; j < 4; ++j) {
            acc[i][j] += a4[i].x * b4[j].x + a4[i].y * b4[j].y +
                         a4[i].z * b4[j].z + a4[i].w * b4[j].w;
          }
      }
    }

    // write prefetched chunk into the other buffer (safe: nobody reads it now)
    if (pf) {
#pragma unroll
      for (int l = 0; l < 4; ++l) {
        const int row = r0 + 8 * l;
        tile[buf ^ 1][row][col4 ^ ((row >> 2) & 7)] = nxt[l];
      }
    }
    __syncthreads();
  }

  // reduce the 4 waves' s-partials
#pragma unroll
  for (int i = 0; i < 4; ++i)
#pragma unroll
    for (int j = 0; j < 4; ++j)
      mtmp[w][(4 * ty + i) * 32 + (4 * tx + j)] = acc[i][j];
  __syncthreads();

  float* __restrict__ po = part + (size_t)blk * 1024;
#pragma unroll
  for (int j = 0; j < 4; ++j) {
    const int e = tid + 256 * j;
    po[e] = (mtmp[0][e] + mtmp[1][e]) + (mtmp[2][e] + mtmp[3][e]);
  }
}

// ---------------------------------------------------------------------------
// Kernel 2: reduce partials over c.  msum[b][e] = sum_c part[b*64+c][e]
// 64 blocks x 256 threads; coalesced strided loads, 4 independent acc chains.
// ---------------------------------------------------------------------------
__global__ __launch_bounds__(256) void reduce_c(const float* __restrict__ part,
                                                float* __restrict__ msum) {
  const int bid = blockIdx.x;                // 0..63
  const int b   = bid >> 2;
  const int e   = (bid & 3) * 256 + threadIdx.x;   // 0..1023
  const float* __restrict__ p = part + (size_t)b * 64 * 1024 + e;
  float s0 = 0.f, s1 = 0.f, s2 = 0.f, s3 = 0.f;
#pragma unroll
  for (int c = 0; c < 64; c += 4) {
    s0 += p[(size_t)(c + 0) * 1024];
    s1 += p[(size_t)(c + 1) * 1024];
    s2 += p[(size_t)(c + 2) * 1024];
    s3 += p[(size_t)(c + 3) * 1024];
  }
  msum[b * 1024 + e] = (s0 + s1) + (s2 + s3);
}

// ---------------------------------------------------------------------------
// Kernel 3: softmax over the BATCH axis (dim 0) for each (q,k).
// ---------------------------------------------------------------------------
__global__ __launch_bounds__(256) void softmax_b(const float* __restrict__ msum,
                                                 float* __restrict__ msoft) {
  const int e = blockIdx.x * 256 + threadIdx.x;    // 0..1023 (q*32+k)
  float l[16];
  float mx = -3.4e38f;
#pragma unroll
  for (int b = 0; b < 16; ++b) {
    l[b] = msum[b * 1024 + e];
    mx = fmaxf(mx, l[b]);
  }
  float s = 0.f;
#pragma unroll
  for (int b = 0; b < 16; ++b) {
    l[b] = expf(l[b] - mx);
    s += l[b];
  }
  const float inv = 1.f / s;
#pragma unroll
  for (int b = 0; b < 16; ++b) msoft[b * 1024 + e] = l[b] * inv;
}

// ---------------------------------------------------------------------------
// Kernel 4: PV.  out[blk][q][s] = sum_k M[b][q][k] * xv[blk][k][s]
// 1024 blocks x 256 threads. xv read directly from global (float4, 8-way
// lane-merge -> perfectly coalesced, each line consumed once). M in LDS
// padded [32][33] so the q-strided broadcast reads are conflict-free.
// ---------------------------------------------------------------------------
__global__ __launch_bounds__(256) void pv(const float* __restrict__ xv,
                                          const float* __restrict__ msoft,
                                          float* __restrict__ out) {
  const int blk = blockIdx.x;                 // b*64 + c
  const int b   = blk >> 6;
  const float* __restrict__ xvb = xv + (size_t)blk * (Tt * Ss);
  float* __restrict__ ob        = out + (size_t)blk * (Tt * Ss);

  __shared__ float M[32 * 33];
  const int tid = threadIdx.x;
#pragma unroll
  for (int j = 0; j < 4; ++j) {
    const int e = tid + 256 * j;              // q*32 + k
    M[(e >> 5) * 33 + (e & 31)] = msoft[b * 1024 + e];
  }
  __syncthreads();

  const int w    = tid >> 6;
  const int lane = tid & 63;
  const int ty   = lane >> 3;                 // q-group
  const int tx   = lane & 7;                  // s-group

  for (int it = 0; it < 7; ++it) {
    const int s4 = it * 32 + w * 8 + tx;      // float4 column index, 0..195
    if (s4 < 196) {
      float4 a0 = {0.f, 0.f, 0.f, 0.f};
      float4 a1 = {0.f, 0.f, 0.f, 0.f};
      float4 a2 = {0.f, 0.f, 0.f, 0.f};
      float4 a3 = {0.f, 0.f, 0.f, 0.f};
#pragma unroll
      for (int k = 0; k < 32; ++k) {
        const float4 v = *reinterpret_cast<const float4*>(xvb + k * Ss + 4 * s4);
        const float m0 = M[(4 * ty + 0) * 33 + k];
        const float m1 = M[(4 * ty + 1) * 33 + k];
        const float m2 = M[(4 * ty + 2) * 33 + k];
        const float m3 = M[(4 * ty + 3) * 33 + k];
        a0.x += m0 * v.x; a0.y += m0 * v.y; a0.z += m0 * v.z; a0.w += m0 * v.w;
        a1.x += m1 * v.x; a1.y += m1 * v.y; a1.z += m1 * v.z; a1.w += m1 * v.w;
        a2.x += m2 * v.x; a2.y += m2 * v.y; a2.z += m2 * v.z; a2.w += m2 * v.w;
        a3.x += m3 * v.x; a3.y += m3 * v.y; a3.z += m3 * v.z; a3.w += m3 * v.w;
      }
      *reinterpret_cast<float4*>(ob + (4 * ty + 0) * Ss + 4 * s4) = a0;
      *reinterpret_cast<float4*>(ob + (4 * ty + 1) * Ss + 4 * s4) = a1;
      *reinterpret_cast<float4*>(ob + (4 * ty + 2) * Ss + 4 * s4) = a2;
      *reinterpret_cast<float4*>(ob + (4 * ty + 3) * Ss + 4 * s4) = a3;
    }
  }
}

}  // namespace

extern "C" void kernel_launch(void* const* d_in, const int* in_sizes, int n_in,
                              void* d_out, int out_size, void* d_ws, size_t ws_size,
                              hipStream_t stream) {
  const float* x  = (const float*)d_in[0];
  const float* xv = (const float*)d_in[1];
  float* out = (float*)d_out;

  // workspace layout (fp32):
  //   part : 1024 * 1024            (4 MiB)   per-(b,c) Gram partials
  //   msum : 16 * 1024              (64 KiB)  reduced logits
  //   msoft: 16 * 1024              (64 KiB)  batch-softmaxed weights
  float* part  = (float*)d_ws;
  float* msum  = part + 1024 * 1024;
  float* msoft = msum + 16 * 1024;

  gram_partial<<<dim3(1024), dim3(256), 0, stream>>>(x, part);
  reduce_c<<<dim3(64), dim3(256), 0, stream>>>(part, msum);
  softmax_b<<<dim3(4), dim3(256), 0, stream>>>(msum, msoft);
  pv<<<dim3(1024), dim3(256), 0, stream>>>(xv, msoft, out);
}